// Round 8
// baseline (3045.648 us; speedup 1.0000x reference)
//
#include <hip/hip_runtime.h>
#include <hip/hip_bf16.h>

#define SEQ 512
#define BATCH 64
#define IN 256
#define HID 512
#define NG 1536  // 3*HID

typedef short short8 __attribute__((ext_vector_type(8)));
typedef float f32x4 __attribute__((ext_vector_type(4)));

__device__ __forceinline__ unsigned short f2bf(float f) {
    union { float f; unsigned u; } v; v.f = f;
    return (unsigned short)((v.u + 0x7fffu + ((v.u >> 16) & 1u)) >> 16);
}
__device__ __forceinline__ float bf2f(unsigned short h) {
    union { unsigned u; float f; } v; v.u = ((unsigned)h) << 16; return v.f;
}

// Build gate-major bf16 weight blocks + folded bias constants.
__global__ void prep_weights(const float* __restrict__ Wr, const float* __restrict__ br,
                             const float* __restrict__ Wu, const float* __restrict__ bu,
                             const float* __restrict__ Wni, const float* __restrict__ bni,
                             const float* __restrict__ Wnh, const float* __restrict__ bnh,
                             unsigned short* __restrict__ WxT, unsigned short* __restrict__ WhT,
                             float* __restrict__ biases)
{
    int n = blockIdx.x * blockDim.x + threadIdx.x;
    if (n >= NG) return;
    int g = n >> 9, j = n & 511;
    const float* xsrc; const float* hsrc; float bias;
    if (g == 0)      { xsrc = Wr + (size_t)j*770; hsrc = Wr + (size_t)j*770 + 257;
                       bias = Wr[(size_t)j*770+256] + Wr[(size_t)j*770+769] + br[j]; }
    else if (g == 1) { xsrc = Wu + (size_t)j*770; hsrc = Wu + (size_t)j*770 + 257;
                       bias = Wu[(size_t)j*770+256] + Wu[(size_t)j*770+769] + bu[j]; }
    else             { xsrc = Wni + (size_t)j*257; hsrc = Wnh + (size_t)j*513;
                       bias = Wni[(size_t)j*257+256] + bni[j]; }
    for (int i = 0; i < IN; ++i)  WxT[(size_t)n*IN + i]  = f2bf(xsrc[i]);
    for (int k = 0; k < HID; ++k) WhT[(size_t)n*HID + k] = f2bf(hsrc[k]);
    biases[n] = bias;
    if (g == 2) biases[NG + j] = Wnh[(size_t)j*513 + 512] + bnh[j];
}

__global__ void cvt_x(const float* __restrict__ x, unsigned short* __restrict__ xb, int n)
{
    int i = (blockIdx.x * blockDim.x + threadIdx.x) * 4;
    if (i >= n) return;
    float4 v = *reinterpret_cast<const float4*>(x + i);
    ushort4 o;
    o.x = f2bf(v.x); o.y = f2bf(v.y); o.z = f2bf(v.z); o.w = f2bf(v.w);
    *reinterpret_cast<ushort4*>(xb + i) = o;
}

// Gx[m][n] = sum_i xb[m][i]*WxT[n][i] + biases[n],  m = t*64+b, stored bf16.
__global__ __launch_bounds__(256) void gemm_x(const unsigned short* __restrict__ xb,
                                              const unsigned short* __restrict__ WxT,
                                              const float* __restrict__ biases,
                                              unsigned short* __restrict__ Gx)
{
    const int lane = threadIdx.x & 63;
    const int wave = threadIdx.x >> 6;
    const int m0 = blockIdx.x * 64;
    const int n0 = blockIdx.y * 256 + wave * 64;
    const int laneM = lane & 15, laneK8 = (lane >> 4) * 8;
    f32x4 acc[4][4] = {};
#pragma unroll
    for (int k0 = 0; k0 < IN; k0 += 32) {
        short8 A[4], Bf[4];
#pragma unroll
        for (int mi = 0; mi < 4; ++mi)
            A[mi] = *reinterpret_cast<const short8*>(xb + (size_t)(m0 + mi*16 + laneM)*IN + k0 + laneK8);
#pragma unroll
        for (int ni = 0; ni < 4; ++ni)
            Bf[ni] = *reinterpret_cast<const short8*>(WxT + (size_t)(n0 + ni*16 + laneM)*IN + k0 + laneK8);
#pragma unroll
        for (int mi = 0; mi < 4; ++mi)
#pragma unroll
            for (int ni = 0; ni < 4; ++ni)
                acc[mi][ni] = __builtin_amdgcn_mfma_f32_16x16x32_bf16(A[mi], Bf[ni], acc[mi][ni], 0, 0, 0);
    }
    const int crow = (lane >> 4) * 4, ccol = lane & 15;
#pragma unroll
    for (int mi = 0; mi < 4; ++mi)
#pragma unroll
        for (int ni = 0; ni < 4; ++ni) {
            int nn = n0 + ni*16 + ccol;
            float bias = biases[nn];
#pragma unroll
            for (int v = 0; v < 4; ++v) {
                int mm = m0 + mi*16 + crow + v;
                Gx[(size_t)mm * NG + nn] = f2bf(acc[mi][ni][v] + bias);
            }
        }
}

// Persistent recurrent kernel. 128 blocks x 256 threads (cooperative launch).
// 8 groups x 8 batch rows; block (g, jt) owns 32 hidden cols.
// Sync is FUSED with data: h words are tagged (tag<<16 | bf16). Each wave's 4
// A-fragments map 1:1 to 4 producer blocks (frag f <- block 4*wave+f), so the
// wave polls its own data words per-frag: re-load ONLY frags whose producer
// hasn't landed (wave-uniform mask via __any). The detecting load IS the data
// load: no digest, no drain, no counter, no post-detect re-sweep.
__global__ __launch_bounds__(256, 1) void gru_seq(const unsigned short* __restrict__ Gx,
                                                  const unsigned short* __restrict__ WhT,
                                                  const float* __restrict__ biases,
                                                  unsigned* __restrict__ htag,
                                                  float* __restrict__ out)
{
    const int blk = blockIdx.x;
    const int g = blk >> 4, jt = blk & 15;        // 8 groups x 16 j-tiles
    const int b0 = g * 8, j0 = jt * 32;
    const int lane = threadIdx.x & 63;
    const int wave = threadIdx.x >> 6;
    const int laneM = lane & 15, laneK8 = (lane >> 4) * 8;
    __shared__ float red[4][3][2][8][16];

    // Preload recurrent weight fragments once: 3 gates x 2 n-tiles x 4 k-frags.
    short8 Bf[3][2][4];
#pragma unroll
    for (int gg = 0; gg < 3; ++gg)
#pragma unroll
        for (int nt = 0; nt < 2; ++nt)
#pragma unroll
            for (int kk = 0; kk < 4; ++kk) {
                int n = gg * HID + j0 + nt * 16 + laneM;
                int k = wave * 128 + kk * 32 + laneK8;
                Bf[gg][nt][kk] = *reinterpret_cast<const short8*>(WhT + (size_t)n * HID + k);
            }

    const int row = threadIdx.x >> 5, col = threadIdx.x & 31;   // 8 x 32 epilogue map
    const int b = b0 + row, jj = j0 + col;
    const float cnh = biases[NG + jj];
    float h_old = 0.f;
    const size_t gx0 = (size_t)b * NG + jj;
    unsigned short pr = Gx[gx0], pu = Gx[gx0 + HID], pn = Gx[gx0 + 2*HID];

    // Per-thread data base: row b0+(laneM&7) (A rows 8-15 mirror 0-7), wave k-slice.
    const size_t kbase = (size_t)(b0 + (laneM & 7)) * HID + wave * 128 + laneK8;

    for (int t = 0; t < SEQ; ++t) {
        // ---- Fused poll: spec-issue all 4 frags, then per-frag masked re-load ----
        const unsigned need = (unsigned)t << 16;
        const unsigned* hp = htag + (size_t)(t & 1) * BATCH * HID + kbase;
        unsigned cur[32];
#pragma unroll
        for (int f = 0; f < 4; ++f)
#pragma unroll
            for (int w = 0; w < 8; ++w)
                cur[f*8+w] = __hip_atomic_load(hp + f*32 + w, __ATOMIC_RELAXED, __HIP_MEMORY_SCOPE_AGENT);
        for (;;) {
            unsigned stale = 0;
#pragma unroll
            for (int f = 0; f < 4; ++f) {
                unsigned bb = 0;
#pragma unroll
                for (int w = 0; w < 8; ++w) bb |= (cur[f*8+w] ^ need) & 0xffff0000u;
                stale |= ((unsigned)(__any(bb != 0) ? 1u : 0u)) << f;
            }
            if (stale == 0) break;
#pragma unroll
            for (int f = 0; f < 4; ++f) {
                if (stale & (1u << f)) {
                    unsigned nw[8];
#pragma unroll
                    for (int w = 0; w < 8; ++w)
                        nw[w] = __hip_atomic_load(hp + f*32 + w, __ATOMIC_RELAXED, __HIP_MEMORY_SCOPE_AGENT);
#pragma unroll
                    for (int w = 0; w < 8; ++w)
                        cur[f*8+w] = ((cur[f*8+w] ^ need) & 0xffff0000u) ? nw[w] : cur[f*8+w];
                }
            }
        }

        // Prefetch next step's x-projections AFTER the poll (keeps the poll's
        // vmcnt retirement free of queued HBM loads; ~1 full step to complete).
        unsigned short nr = 0, nu = 0, nn2 = 0;
        if (t + 1 < SEQ) {
            size_t gi = gx0 + (size_t)(t + 1) * BATCH * NG;
            nr = Gx[gi]; nu = Gx[gi + HID]; nn2 = Gx[gi + 2*HID];
        }

        // Pack bf16 payloads into MFMA A fragments.
        short8 A[4];
#pragma unroll
        for (int kk = 0; kk < 4; ++kk) {
            union { unsigned p[4]; short8 s; } pk;
#pragma unroll
            for (int i = 0; i < 4; ++i)
                pk.p[i] = (cur[kk*8 + 2*i] & 0xffffu) | (cur[kk*8 + 2*i + 1] << 16);
            A[kk] = pk.s;
        }

        f32x4 acc[3][2] = {};
#pragma unroll
        for (int kk = 0; kk < 4; ++kk)
#pragma unroll
            for (int gg = 0; gg < 3; ++gg)
#pragma unroll
                for (int nt = 0; nt < 2; ++nt)
                    acc[gg][nt] = __builtin_amdgcn_mfma_f32_16x16x32_bf16(A[kk], Bf[gg][nt][kk], acc[gg][nt], 0, 0, 0);

        __syncthreads();   // previous iteration's epilogue reads of red[] done
        const int crow = (lane >> 4) * 4;
        if (crow < 8) {
#pragma unroll
            for (int v = 0; v < 4; ++v)
#pragma unroll
                for (int gg = 0; gg < 3; ++gg)
#pragma unroll
                    for (int nt = 0; nt < 2; ++nt)
                        red[wave][gg][nt][crow + v][laneM] = acc[gg][nt][v];
        }
        __syncthreads();
        const int nt = col >> 4, c16 = col & 15;
        float rp = red[0][0][nt][row][c16] + red[1][0][nt][row][c16] + red[2][0][nt][row][c16] + red[3][0][nt][row][c16];
        float up = red[0][1][nt][row][c16] + red[1][1][nt][row][c16] + red[2][1][nt][row][c16] + red[3][1][nt][row][c16];
        float np = red[0][2][nt][row][c16] + red[1][2][nt][row][c16] + red[2][2][nt][row][c16] + red[3][2][nt][row][c16];
        float r = 1.f / (1.f + __expf(-(bf2f(pr) + rp)));
        float z = 1.f / (1.f + __expf(-(bf2f(pu) + up)));
        float e = __expf(2.f * (bf2f(pn) + r * (np + cnh)));
        float n = 1.f - 2.f / (e + 1.f);
        float hnew = (1.f - z) * n + z * h_old;
        h_old = hnew;

        // Publish tagged h_{t+1} FIRST (fire and forget), then out[] stores.
        __hip_atomic_store(htag + (size_t)((t + 1) & 1) * BATCH * HID + (size_t)b * HID + jj,
                           ((unsigned)(t + 1) << 16) | (unsigned)f2bf(hnew),
                           __ATOMIC_RELAXED, __HIP_MEMORY_SCOPE_AGENT);
        out[(size_t)t * BATCH * HID + (size_t)b * HID + jj] = hnew;
        if (t == SEQ - 1) out[(size_t)SEQ * BATCH * HID + (size_t)b * HID + jj] = hnew;
        pr = nr; pu = nu; pn = nn2;
    }
}

extern "C" void kernel_launch(void* const* d_in, const int* in_sizes, int n_in,
                              void* d_out, int out_size, void* d_ws, size_t ws_size,
                              hipStream_t stream)
{
    const float* x   = (const float*)d_in[0];
    const float* Wr  = (const float*)d_in[1];
    const float* br  = (const float*)d_in[2];
    const float* Wu  = (const float*)d_in[3];
    const float* bu  = (const float*)d_in[4];
    const float* Wni = (const float*)d_in[5];
    const float* bni = (const float*)d_in[6];
    const float* Wnh = (const float*)d_in[7];
    const float* bnh = (const float*)d_in[8];
    float* out = (float*)d_out;

    char* ws = (char*)d_ws;
    size_t off = 0;
    unsigned short* Gx  = (unsigned short*)(ws + off); off += (size_t)SEQ*BATCH*NG*2;   // 100.7 MB
    unsigned short* xb  = (unsigned short*)(ws + off); off += (size_t)SEQ*BATCH*IN*2;   // 16.8 MB
    unsigned short* WxT = (unsigned short*)(ws + off); off += (size_t)NG*IN*2;
    unsigned short* WhT = (unsigned short*)(ws + off); off += (size_t)NG*HID*2;
    float* biases       = (float*)(ws + off);          off += (size_t)(NG+HID)*4;
    unsigned* htag      = (unsigned*)(ws + off);       off += (size_t)2*BATCH*HID*4;    // 256 KB tagged h
    if (ws_size < off) return;

    hipLaunchKernelGGL(prep_weights, dim3(6), dim3(256), 0, stream,
                       Wr, br, Wu, bu, Wni, bni, Wnh, bnh, WxT, WhT, biases);
    hipLaunchKernelGGL(cvt_x, dim3(8192), dim3(256), 0, stream, x, xb, SEQ*BATCH*IN);
    hipLaunchKernelGGL(gemm_x, dim3(512, 6), dim3(256), 0, stream, xb, WxT, biases, Gx);
    // Zero tagged-h (tag 0 == valid h_0 == zeros).
    hipMemsetAsync(htag, 0, (size_t)2*BATCH*HID*4, stream);

    void* args[] = { &Gx, &WhT, &biases, &htag, &out };
    hipLaunchCooperativeKernel((void*)gru_seq, dim3(128), dim3(256), args, 0, stream);
}

// Round 9
// 2239.698 us; speedup vs baseline: 1.3598x; 1.3598x over previous
//
#include <hip/hip_runtime.h>
#include <hip/hip_bf16.h>

#define SEQ 512
#define BATCH 64
#define IN 256
#define HID 512
#define NG 1536  // 3*HID

typedef short short8 __attribute__((ext_vector_type(8)));
typedef float f32x4 __attribute__((ext_vector_type(4)));

__device__ __forceinline__ unsigned short f2bf(float f) {
    union { float f; unsigned u; } v; v.f = f;
    return (unsigned short)((v.u + 0x7fffu + ((v.u >> 16) & 1u)) >> 16);
}
__device__ __forceinline__ float bf2f(unsigned short h) {
    union { unsigned u; float f; } v; v.u = ((unsigned)h) << 16; return v.f;
}

// Build gate-major bf16 weight blocks + folded bias constants.
__global__ void prep_weights(const float* __restrict__ Wr, const float* __restrict__ br,
                             const float* __restrict__ Wu, const float* __restrict__ bu,
                             const float* __restrict__ Wni, const float* __restrict__ bni,
                             const float* __restrict__ Wnh, const float* __restrict__ bnh,
                             unsigned short* __restrict__ WxT, unsigned short* __restrict__ WhT,
                             float* __restrict__ biases)
{
    int n = blockIdx.x * blockDim.x + threadIdx.x;
    if (n >= NG) return;
    int g = n >> 9, j = n & 511;
    const float* xsrc; const float* hsrc; float bias;
    if (g == 0)      { xsrc = Wr + (size_t)j*770; hsrc = Wr + (size_t)j*770 + 257;
                       bias = Wr[(size_t)j*770+256] + Wr[(size_t)j*770+769] + br[j]; }
    else if (g == 1) { xsrc = Wu + (size_t)j*770; hsrc = Wu + (size_t)j*770 + 257;
                       bias = Wu[(size_t)j*770+256] + Wu[(size_t)j*770+769] + bu[j]; }
    else             { xsrc = Wni + (size_t)j*257; hsrc = Wnh + (size_t)j*513;
                       bias = Wni[(size_t)j*257+256] + bni[j]; }
    for (int i = 0; i < IN; ++i)  WxT[(size_t)n*IN + i]  = f2bf(xsrc[i]);
    for (int k = 0; k < HID; ++k) WhT[(size_t)n*HID + k] = f2bf(hsrc[k]);
    biases[n] = bias;
    if (g == 2) biases[NG + j] = Wnh[(size_t)j*513 + 512] + bnh[j];
}

__global__ void cvt_x(const float* __restrict__ x, unsigned short* __restrict__ xb, int n)
{
    int i = (blockIdx.x * blockDim.x + threadIdx.x) * 4;
    if (i >= n) return;
    float4 v = *reinterpret_cast<const float4*>(x + i);
    ushort4 o;
    o.x = f2bf(v.x); o.y = f2bf(v.y); o.z = f2bf(v.z); o.w = f2bf(v.w);
    *reinterpret_cast<ushort4*>(xb + i) = o;
}

// Gx[m][n] = sum_i xb[m][i]*WxT[n][i] + biases[n],  m = t*64+b, stored bf16.
__global__ __launch_bounds__(256) void gemm_x(const unsigned short* __restrict__ xb,
                                              const unsigned short* __restrict__ WxT,
                                              const float* __restrict__ biases,
                                              unsigned short* __restrict__ Gx)
{
    const int lane = threadIdx.x & 63;
    const int wave = threadIdx.x >> 6;
    const int m0 = blockIdx.x * 64;
    const int n0 = blockIdx.y * 256 + wave * 64;
    const int laneM = lane & 15, laneK8 = (lane >> 4) * 8;
    f32x4 acc[4][4] = {};
#pragma unroll
    for (int k0 = 0; k0 < IN; k0 += 32) {
        short8 A[4], Bf[4];
#pragma unroll
        for (int mi = 0; mi < 4; ++mi)
            A[mi] = *reinterpret_cast<const short8*>(xb + (size_t)(m0 + mi*16 + laneM)*IN + k0 + laneK8);
#pragma unroll
        for (int ni = 0; ni < 4; ++ni)
            Bf[ni] = *reinterpret_cast<const short8*>(WxT + (size_t)(n0 + ni*16 + laneM)*IN + k0 + laneK8);
#pragma unroll
        for (int mi = 0; mi < 4; ++mi)
#pragma unroll
            for (int ni = 0; ni < 4; ++ni)
                acc[mi][ni] = __builtin_amdgcn_mfma_f32_16x16x32_bf16(A[mi], Bf[ni], acc[mi][ni], 0, 0, 0);
    }
    const int crow = (lane >> 4) * 4, ccol = lane & 15;
#pragma unroll
    for (int mi = 0; mi < 4; ++mi)
#pragma unroll
        for (int ni = 0; ni < 4; ++ni) {
            int nn = n0 + ni*16 + ccol;
            float bias = biases[nn];
#pragma unroll
            for (int v = 0; v < 4; ++v) {
                int mm = m0 + mi*16 + crow + v;
                Gx[(size_t)mm * NG + nn] = f2bf(acc[mi][ni][v] + bias);
            }
        }
}

// Persistent recurrent kernel. 128 blocks x 256 threads (cooperative launch).
// 8 groups x 8 batch rows; block (g, jt) owns 32 hidden cols. Per step:
//   producer wave: publish tagged h words + out[] stores -> s_waitcnt vmcnt(0)
//                  (drains ONLY its own 2-3 stores) -> lane0 stores per-WAVE
//                  digest = t+1. No block barrier on the digest path.
//   consumer wave w: polls the 16 wave-digests of ITS 4 producer blocks
//                  (4w..4w+3; one 16-lane load of consecutive 64B lines);
//                  digest >= t implies data ACKED at the coherence point ->
//                  ONE guaranteed-fresh 32-word sweep; tag-validate loop is a
//                  safety net that normally never iterates.
// FIFO-vmcnt hygiene: no loads/stores left outstanding when the poll spins
// (Gx prefetch issued right after the data sweep; publish/out drained before
// the digest store).
__global__ __launch_bounds__(256, 1) void gru_seq(const unsigned short* __restrict__ Gx,
                                                  const unsigned short* __restrict__ WhT,
                                                  const float* __restrict__ biases,
                                                  unsigned* __restrict__ htag,
                                                  unsigned* __restrict__ dig,
                                                  float* __restrict__ out)
{
    const int blk = blockIdx.x;
    const int g = blk >> 4, jt = blk & 15;        // 8 groups x 16 j-tiles
    const int b0 = g * 8, j0 = jt * 32;
    const int lane = threadIdx.x & 63;
    const int wave = threadIdx.x >> 6;
    const int laneM = lane & 15, laneK8 = (lane >> 4) * 8;
    __shared__ float red[4][3][2][8][16];

    // Preload recurrent weight fragments once: 3 gates x 2 n-tiles x 4 k-frags.
    short8 Bf[3][2][4];
#pragma unroll
    for (int gg = 0; gg < 3; ++gg)
#pragma unroll
        for (int nt = 0; nt < 2; ++nt)
#pragma unroll
            for (int kk = 0; kk < 4; ++kk) {
                int n = gg * HID + j0 + nt * 16 + laneM;
                int k = wave * 128 + kk * 32 + laneK8;
                Bf[gg][nt][kk] = *reinterpret_cast<const short8*>(WhT + (size_t)n * HID + k);
            }

    const int row = threadIdx.x >> 5, col = threadIdx.x & 31;   // 8 x 32 epilogue map
    const int b = b0 + row, jj = j0 + col;
    const float cnh = biases[NG + jj];
    float h_old = 0.f;
    const size_t gx0 = (size_t)b * NG + jj;
    unsigned short pr = Gx[gx0], pu = Gx[gx0 + HID], pn = Gx[gx0 + 2*HID];

    // Per-thread data base: row b0+(laneM&7) (A rows 8-15 mirror 0-7), wave k-slice.
    const size_t kbase = (size_t)(b0 + (laneM & 7)) * HID + wave * 128 + laneK8;
    // Wave w consumes blocks 4w..4w+3 -> their 16 wave-digests are consecutive:
    // dig[(g*64 + 16*w + l)*16], l = lane 0..15.  Producer digest: (g*64+jt*4+wave).
    const unsigned* pollp = dig + ((size_t)g * 64 + (size_t)wave * 16 + (lane & 15)) * 16;
    unsigned* mydig = dig + ((size_t)g * 64 + (size_t)jt * 4 + wave) * 16;

    for (int t = 0; t < SEQ; ++t) {
        // ---- Digest poll: wave waits only ITS 4 producer blocks (16 waves) ----
        if (t > 0) {
            const unsigned tgt = (unsigned)t;
            unsigned v;
            do {
                v = (lane < 16)
                    ? __hip_atomic_load(pollp, __ATOMIC_RELAXED, __HIP_MEMORY_SCOPE_AGENT)
                    : tgt;
            } while (!__all(v >= tgt));
        }

        // ---- One guaranteed-fresh data sweep (producers drained pre-digest) ----
        const unsigned need = (unsigned)t << 16;
        const unsigned* hp = htag + (size_t)(t & 1) * BATCH * HID + kbase;
        unsigned cur[32];
#pragma unroll
        for (int f = 0; f < 4; ++f)
#pragma unroll
            for (int w = 0; w < 8; ++w)
                cur[f*8+w] = __hip_atomic_load(hp + f*32 + w, __ATOMIC_RELAXED, __HIP_MEMORY_SCOPE_AGENT);
        // Safety net (normally zero iterations).
        unsigned bad = 0;
#pragma unroll
        for (int w = 0; w < 32; ++w) bad |= (cur[w] ^ need) & 0xffff0000u;
        while (!__all(bad == 0)) {
            unsigned nw[32];
#pragma unroll
            for (int f = 0; f < 4; ++f)
#pragma unroll
                for (int w = 0; w < 8; ++w)
                    nw[f*8+w] = __hip_atomic_load(hp + f*32 + w, __ATOMIC_RELAXED, __HIP_MEMORY_SCOPE_AGENT);
            bad = 0;
#pragma unroll
            for (int w = 0; w < 32; ++w) {
                cur[w] = ((cur[w] ^ need) & 0xffff0000u) ? nw[w] : cur[w];
                bad |= (cur[w] ^ need) & 0xffff0000u;
            }
        }

        // Gx prefetch for t+1 NOW: retires during MFMA/reduce, so it is gone
        // before the tail drain and the next poll (FIFO-vmcnt hygiene).
        unsigned short nr = 0, nu = 0, nn2 = 0;
        if (t + 1 < SEQ) {
            size_t gi = gx0 + (size_t)(t + 1) * BATCH * NG;
            nr = Gx[gi]; nu = Gx[gi + HID]; nn2 = Gx[gi + 2*HID];
        }

        // Pack bf16 payloads into MFMA A fragments.
        short8 A[4];
#pragma unroll
        for (int kk = 0; kk < 4; ++kk) {
            union { unsigned p[4]; short8 s; } pk;
#pragma unroll
            for (int i = 0; i < 4; ++i)
                pk.p[i] = (cur[kk*8 + 2*i] & 0xffffu) | (cur[kk*8 + 2*i + 1] << 16);
            A[kk] = pk.s;
        }

        f32x4 acc[3][2] = {};
#pragma unroll
        for (int kk = 0; kk < 4; ++kk)
#pragma unroll
            for (int gg = 0; gg < 3; ++gg)
#pragma unroll
                for (int nt = 0; nt < 2; ++nt)
                    acc[gg][nt] = __builtin_amdgcn_mfma_f32_16x16x32_bf16(A[kk], Bf[gg][nt][kk], acc[gg][nt], 0, 0, 0);

        __syncthreads();   // WAR: previous iteration's epilogue reads of red[] done
        const int crow = (lane >> 4) * 4;
        if (crow < 8) {
#pragma unroll
            for (int v = 0; v < 4; ++v)
#pragma unroll
                for (int gg = 0; gg < 3; ++gg)
#pragma unroll
                    for (int nt = 0; nt < 2; ++nt)
                        red[wave][gg][nt][crow + v][laneM] = acc[gg][nt][v];
        }
        __syncthreads();
        const int nt = col >> 4, c16 = col & 15;
        float rp = red[0][0][nt][row][c16] + red[1][0][nt][row][c16] + red[2][0][nt][row][c16] + red[3][0][nt][row][c16];
        float up = red[0][1][nt][row][c16] + red[1][1][nt][row][c16] + red[2][1][nt][row][c16] + red[3][1][nt][row][c16];
        float np = red[0][2][nt][row][c16] + red[1][2][nt][row][c16] + red[2][2][nt][row][c16] + red[3][2][nt][row][c16];
        float r = 1.f / (1.f + __expf(-(bf2f(pr) + rp)));
        float z = 1.f / (1.f + __expf(-(bf2f(pu) + up)));
        float e = __expf(2.f * (bf2f(pn) + r * (np + cnh)));
        float n = 1.f - 2.f / (e + 1.f);
        float hnew = (1.f - z) * n + z * h_old;
        h_old = hnew;

        // Publish tagged h_{t+1} and out[] stores, then per-wave drain: the
        // only outstanding VM ops are these 2-3 stores (Gx retired by now).
        __hip_atomic_store(htag + (size_t)((t + 1) & 1) * BATCH * HID + (size_t)b * HID + jj,
                           ((unsigned)(t + 1) << 16) | (unsigned)f2bf(hnew),
                           __ATOMIC_RELAXED, __HIP_MEMORY_SCOPE_AGENT);
        out[(size_t)t * BATCH * HID + (size_t)b * HID + jj] = hnew;
        if (t == SEQ - 1) out[(size_t)SEQ * BATCH * HID + (size_t)b * HID + jj] = hnew;
        asm volatile("s_waitcnt vmcnt(0)" ::: "memory");
        // Per-wave digest: data for rows {2*wave, 2*wave+1} x cols [j0,j0+32) ACKED.
        if (lane == 0)
            __hip_atomic_store(mydig, (unsigned)(t + 1), __ATOMIC_RELAXED, __HIP_MEMORY_SCOPE_AGENT);
        pr = nr; pu = nu; pn = nn2;
    }
}

extern "C" void kernel_launch(void* const* d_in, const int* in_sizes, int n_in,
                              void* d_out, int out_size, void* d_ws, size_t ws_size,
                              hipStream_t stream)
{
    const float* x   = (const float*)d_in[0];
    const float* Wr  = (const float*)d_in[1];
    const float* br  = (const float*)d_in[2];
    const float* Wu  = (const float*)d_in[3];
    const float* bu  = (const float*)d_in[4];
    const float* Wni = (const float*)d_in[5];
    const float* bni = (const float*)d_in[6];
    const float* Wnh = (const float*)d_in[7];
    const float* bnh = (const float*)d_in[8];
    float* out = (float*)d_out;

    char* ws = (char*)d_ws;
    size_t off = 0;
    unsigned short* Gx  = (unsigned short*)(ws + off); off += (size_t)SEQ*BATCH*NG*2;   // 100.7 MB
    unsigned short* xb  = (unsigned short*)(ws + off); off += (size_t)SEQ*BATCH*IN*2;   // 16.8 MB
    unsigned short* WxT = (unsigned short*)(ws + off); off += (size_t)NG*IN*2;
    unsigned short* WhT = (unsigned short*)(ws + off); off += (size_t)NG*HID*2;
    float* biases       = (float*)(ws + off);          off += (size_t)(NG+HID)*4;
    unsigned* htag      = (unsigned*)(ws + off);       off += (size_t)2*BATCH*HID*4;    // 256 KB tagged h
    unsigned* dig       = (unsigned*)(ws + off);       off += (size_t)8*64*16*4;        // 32 KB wave-digests
    if (ws_size < off) return;

    hipLaunchKernelGGL(prep_weights, dim3(6), dim3(256), 0, stream,
                       Wr, br, Wu, bu, Wni, bni, Wnh, bnh, WxT, WhT, biases);
    hipLaunchKernelGGL(cvt_x, dim3(8192), dim3(256), 0, stream, x, xb, SEQ*BATCH*IN);
    hipLaunchKernelGGL(gemm_x, dim3(512, 6), dim3(256), 0, stream, xb, WxT, biases, Gx);
    // Zero tagged-h + digests (contiguous; tag/digest 0 == valid h_0 == zeros).
    hipMemsetAsync(htag, 0, (size_t)2*BATCH*HID*4 + (size_t)8*64*16*4, stream);

    void* args[] = { &Gx, &WhT, &biases, &htag, &dig, &out };
    hipLaunchCooperativeKernel((void*)gru_seq, dim3(128), dim3(256), args, 0, stream);
}